// Round 3
// baseline (328.546 us; speedup 1.0000x reference)
//
#include <hip/hip_runtime.h>
#include <math.h>

typedef __attribute__((ext_vector_type(8)))  short bf16x8;   // 8 bf16 = 4 VGPR
typedef __attribute__((ext_vector_type(16))) float f32x16;   // 32x32 MFMA acc
typedef __attribute__((ext_vector_type(4)))  float f32x4;
typedef __attribute__((ext_vector_type(4)))  unsigned uint4v;

#define MFMA32(a, b, c) __builtin_amdgcn_mfma_f32_32x32x16_bf16((a), (b), (c), 0, 0, 0)

namespace {
constexpr int HWF   = 256;
constexpr int MEMD  = 1024;
constexpr int NROWS = 65536;
constexpr int TM    = 128;          // token rows per block: 4 waves x 32 rows
constexpr int NT    = MEMD / 32;    // 32 j-tiles of 32
constexpr int THREADS = 256;        // 4 waves -> 2 blocks/CU
constexpr float C1v  = 0.01f;
constexpr float C2v  = 0.03f;
constexpr float EPSv = 1e-8f;
constexpr float RK   = 1.0f / 255.0f;

// LDS map (bytes): K dbuf | V dbuf | stats (one-shot SoA) | l-redistribute
constexpr int KB0 = 0;              // 16 KB K tile (32 rows x 512B, xor-swizzled)
constexpr int KB1 = 16384;
constexpr int VB0 = 32768;          // 16 KB V tile (256 rows x 64B, xor-swizzled)
constexpr int VB1 = 49152;
constexpr int STATS = 65536;        // 12 KB: sa[1024] | sb[1024] | sc[1024]
constexpr int LRED  = STATS + 12288;  // 4 waves x 32 x f32 = 512 B
constexpr int SMEM_SZ = LRED + 512;   // 78336 B -> 2 blocks/CU
}

__device__ __forceinline__ short f2bf(float f) {            // RNE float->bf16
    union { float f; unsigned u; } v; v.f = f;
    unsigned r = v.u + 0x7fffu + ((v.u >> 16) & 1u);
    return (short)(r >> 16);
}

// packed f32 pair -> 2 bf16 in one u32 (src0 -> [15:0], src1 -> [31:16])
__device__ __forceinline__ unsigned cvtpk(float a, float b) {
    unsigned r;
    asm("v_cvt_pk_bf16_f32 %0, %1, %2" : "=v"(r) : "v"(a), "v"(b));
    return r;
}

// v_permlane32_swap_b32: a.lanes[32..63] <-> b.lanes[0..31].
__device__ __forceinline__ void plswap(unsigned &a, unsigned &b) {
#if defined(__has_builtin) && __has_builtin(__builtin_amdgcn_permlane32_swap)
    auto r = __builtin_amdgcn_permlane32_swap((int)a, (int)b, false, false);
    a = (unsigned)r[0]; b = (unsigned)r[1];
#else
    const bool h = (threadIdx.x & 32) != 0;
    const unsigned ax = (unsigned)__shfl_xor((int)a, 32);
    const unsigned bx = (unsigned)__shfl_xor((int)b, 32);
    const unsigned na = h ? bx : a;
    const unsigned nb = h ? b : ax;
    a = na; b = nb;
#endif
}

// async global->LDS DMA: 16 KB tile, wave w (of 4) copies [w*4096, w*4096+4096)
__device__ __forceinline__ void dma_tile16(const short* gbase, char* smem, int ldsbase,
                                           int wave, int lane) {
    const char* g = (const char*)gbase + wave * 4096 + lane * 16;
    char* l = smem + ldsbase + wave * 4096;
    #pragma unroll
    for (int i = 0; i < 4; ++i) {
        __builtin_amdgcn_global_load_lds(
            (const __attribute__((address_space(1))) unsigned int*)(g + i * 1024),
            (__attribute__((address_space(3))) unsigned int*)(l + i * 1024), 16, 0, 0);
    }
}

// ---------------------------------------------------------------------------
// prep_w: blocks 0..15 transpose Wk -> WkT, 16..31 Wv -> WvT (64x64 LDS tiles,
// coalesced both ways), blocks 32..39 cast Wq -> bf16.
// ---------------------------------------------------------------------------
__global__ __launch_bounds__(256) void prep_w(
    const float* __restrict__ Wq, const float* __restrict__ Wk,
    const float* __restrict__ Wv, short* __restrict__ wq_bf,
    float* __restrict__ WkT, float* __restrict__ WvT)
{
    __shared__ float tl[64][65];
    const int b = blockIdx.x, t = threadIdx.x;
    if (b < 32) {
        const float* src = (b < 16) ? Wk : Wv;
        float* dst = (b < 16) ? WkT : WvT;
        const int tile = b & 15, tr0 = (tile >> 2) * 64, tc0 = (tile & 3) * 64;
        #pragma unroll
        for (int k2 = 0; k2 < 16; ++k2) {
            const int lin = k2 * 256 + t, r = lin >> 6, c = lin & 63;
            tl[r][c] = src[(size_t)(tr0 + r) * HWF + tc0 + c];
        }
        __syncthreads();
        #pragma unroll
        for (int k2 = 0; k2 < 16; ++k2) {
            const int lin = k2 * 256 + t, c = lin >> 6, r = lin & 63;
            dst[(size_t)(tc0 + c) * HWF + tr0 + r] = tl[r][c];
        }
    } else {
        const int base = (b - 32) * 8192;
        #pragma unroll
        for (int k2 = 0; k2 < 32; ++k2) {
            const int i = base + k2 * 256 + t;
            wq_bf[i] = f2bf(Wq[i]);
        }
    }
}

// ---------------------------------------------------------------------------
// prep_kv (coalesced): 128 blocks x 8 j-slots. Wave w owns j-pair
// {j0+2w, j0+2w+1}; lane ln owns features 4*ln..4*ln+3. W reads are float4
// row-vectors of WkT/WvT (lane-consecutive 16B -> coalesced 1KB/wave-load).
// fp32 accumulate -> identical numerics class as previous prep.
// Blob tile format == exact LDS image consumed by attn (DMA-able).
// ---------------------------------------------------------------------------
__global__ __launch_bounds__(256) void prep_kv(
    const float* __restrict__ mem, const float* __restrict__ WkT,
    const float* __restrict__ WvT, short* __restrict__ kblob,
    short* __restrict__ vblob, float* __restrict__ sblob)
{
    __shared__ __align__(16) float mrows[8][HWF];
    const int t = threadIdx.x, j0 = blockIdx.x * 8;
    #pragma unroll
    for (int k2 = 0; k2 < 8; ++k2) {
        const int lin = k2 * 256 + t;
        mrows[lin >> 8][lin & 255] = mem[(size_t)j0 * HWF + lin];
    }
    __syncthreads();

    const int w = t >> 6, ln = t & 63;
    const int ja = j0 + 2 * w, jb = ja + 1;
    float ka[4] = {0,0,0,0}, kb_[4] = {0,0,0,0};
    float va[4] = {0,0,0,0}, vb_[4] = {0,0,0,0};
    const float4* wkT4 = reinterpret_cast<const float4*>(WkT) + ln;
    const float4* wvT4 = reinterpret_cast<const float4*>(WvT) + ln;

    for (int c4 = 0; c4 < 64; ++c4) {
        const float4 m0 = reinterpret_cast<const float4*>(mrows[2 * w])[c4];
        const float4 m1 = reinterpret_cast<const float4*>(mrows[2 * w + 1])[c4];
        const float m0a[4] = {m0.x, m0.y, m0.z, m0.w};
        const float m1a[4] = {m1.x, m1.y, m1.z, m1.w};
        #pragma unroll
        for (int e = 0; e < 4; ++e) {
            const int c = 4 * c4 + e;
            const float4 wk = wkT4[c * 64];
            const float4 wv = wvT4[c * 64];
            ka[0]  = __builtin_fmaf(m0a[e], wk.x, ka[0]);
            ka[1]  = __builtin_fmaf(m0a[e], wk.y, ka[1]);
            ka[2]  = __builtin_fmaf(m0a[e], wk.z, ka[2]);
            ka[3]  = __builtin_fmaf(m0a[e], wk.w, ka[3]);
            kb_[0] = __builtin_fmaf(m1a[e], wk.x, kb_[0]);
            kb_[1] = __builtin_fmaf(m1a[e], wk.y, kb_[1]);
            kb_[2] = __builtin_fmaf(m1a[e], wk.z, kb_[2]);
            kb_[3] = __builtin_fmaf(m1a[e], wk.w, kb_[3]);
            va[0]  = __builtin_fmaf(m0a[e], wv.x, va[0]);
            va[1]  = __builtin_fmaf(m0a[e], wv.y, va[1]);
            va[2]  = __builtin_fmaf(m0a[e], wv.z, va[2]);
            va[3]  = __builtin_fmaf(m0a[e], wv.w, va[3]);
            vb_[0] = __builtin_fmaf(m1a[e], wv.x, vb_[0]);
            vb_[1] = __builtin_fmaf(m1a[e], wv.y, vb_[1]);
            vb_[2] = __builtin_fmaf(m1a[e], wv.z, vb_[2]);
            vb_[3] = __builtin_fmaf(m1a[e], wv.w, vb_[3]);
        }
    }

    // per-j mean (over 256 features = 4 per lane x 64 lanes), butterfly
    float sa = ka[0] + ka[1] + ka[2] + ka[3];
    float sb = kb_[0] + kb_[1] + kb_[2] + kb_[3];
    #pragma unroll
    for (int m = 1; m < 64; m <<= 1) { sa += __shfl_xor(sa, m); sb += __shfl_xor(sb, m); }
    const float kma = sa * (1.f / HWF), kmb = sb * (1.f / HWF);
    float kca[4], kcb[4];
    #pragma unroll
    for (int e = 0; e < 4; ++e) { kca[e] = ka[e] - kma; kcb[e] = kb_[e] - kmb; }
    float qa = kca[0]*kca[0] + kca[1]*kca[1] + kca[2]*kca[2] + kca[3]*kca[3];
    float qb = kcb[0]*kcb[0] + kcb[1]*kcb[1] + kcb[2]*kcb[2] + kcb[3]*kcb[3];
    #pragma unroll
    for (int m = 1; m < 64; m <<= 1) { qa += __shfl_xor(qa, m); qb += __shfl_xor(qb, m); }
    const float kva = qa * (1.f / (HWF - 1)), kvb = qb * (1.f / (HWF - 1));

    // K blob: [jt][row ro (j), 32 rows][512B: chunk(f>>3)^(ro&7)][8 bf16]
    const int jt = ja >> 5, roa = ja & 31, rob = jb & 31;
    {
        const int chk = ln >> 1, off = 4 * (ln & 1);
        short4 s4a, s4b;
        s4a.x = f2bf(kca[0]); s4a.y = f2bf(kca[1]); s4a.z = f2bf(kca[2]); s4a.w = f2bf(kca[3]);
        s4b.x = f2bf(kcb[0]); s4b.y = f2bf(kcb[1]); s4b.z = f2bf(kcb[2]); s4b.w = f2bf(kcb[3]);
        *reinterpret_cast<short4*>(kblob + jt * 8192 + roa * 256 +
                                   ((chk ^ (roa & 7)) * 8) + off) = s4a;
        *reinterpret_cast<short4*>(kblob + jt * 8192 + rob * 256 +
                                   ((chk ^ (rob & 7)) * 8) + off) = s4b;
    }
    // V blob: [jt][row f (feature)][64B: 4 chunks(j>>3) ^ ((f>>1)&3)][8 bf16 over j]
    #pragma unroll
    for (int e = 0; e < 4; ++e) {
        const int f = 4 * ln + e;
        const int key = (f >> 1) & 3;
        short2 s2; s2.x = f2bf(va[e]); s2.y = f2bf(vb_[e]);
        *reinterpret_cast<short2*>(vblob + jt * 8192 + f * 32 +
                                   (((roa >> 3) ^ key) * 8) + (roa & 7)) = s2;
    }
    if (ln == 0) {
        sblob[ja]        = 2.f * kma;
        sblob[1024 + ja] = kma * kma + C1v;
        sblob[2048 + ja] = kva + C2v;
        sblob[jb]        = 2.f * kmb;
        sblob[1024 + jb] = kmb * kmb + C1v;
        sblob[2048 + jb] = kvb + C2v;
    }
}

// ---------------------------------------------------------------------------
// attn: TM=128 rows/block, 4 waves, 2 blocks/CU. Swapped-operand MFMA chain
// keeps P in registers. Changes this round: V xor-swizzle keyed on (c>>1)&3
// (32-bank coverage for 64B rows); QK accumulator split into 2 independent
// MFMA chains.
// MFMA 32x32x16 layouts (HW-verified m74/m101):
//   A[m=lane&31][k=8*(lane>>5)+e], B[k=8*(lane>>5)+e][n=lane&31],
//   D col=lane&31, row=(reg&3)+8*(reg>>2)+4*(lane>>5).
// ---------------------------------------------------------------------------
__global__ __launch_bounds__(THREADS, 2) void attn(
    const float* __restrict__ x, const short* __restrict__ wq_bf,
    const short* __restrict__ kblob, const short* __restrict__ vblob,
    const float* __restrict__ sblob, float* __restrict__ out)
{
    __shared__ __align__(16) char smem[SMEM_SZ];
    const int t = threadIdx.x, wave = t >> 6, lane = t & 63;
    const int lo = lane & 31, hi = lane >> 5;
    const int rg = wave;                    // 4 row-groups of 32 tokens
    const int n0 = blockIdx.x * TM;
    const int tok = n0 + 32 * rg + lo;      // this lane's token row

    // ---- DMA tile 0 + one-shot stats immediately (overlaps whole prologue) ----
    dma_tile16(kblob, smem, KB0, wave, lane);
    dma_tile16(vblob, smem, VB0, wave, lane);
    #pragma unroll
    for (int r = 0; r < 3; ++r) {           // 12 KB stats: 3 rounds x 4 waves x 1 KB
        __builtin_amdgcn_global_load_lds(
            (const __attribute__((address_space(1))) unsigned int*)
                ((const char*)sblob + r * 4096 + wave * 1024 + lane * 16),
            (__attribute__((address_space(3))) unsigned int*)
                (smem + STATS + r * 4096 + wave * 1024 + lane * 16), 16, 0, 0);
    }

    // ---- x B-frags: lane = token (n index), regs = feature ----
    bf16x8 xB[16];
    {
        const float* xr = x + (size_t)tok * HWF;
        #pragma unroll
        for (int s = 0; s < 16; ++s) {
            const float4 a = *reinterpret_cast<const float4*>(xr + 16 * s + 8 * hi);
            const float4 b = *reinterpret_cast<const float4*>(xr + 16 * s + 8 * hi + 4);
            uint4v u;
            u[0] = cvtpk(a.x, a.y); u[1] = cvtpk(a.z, a.w);
            u[2] = cvtpk(b.x, b.y); u[3] = cvtpk(b.z, b.w);
            xB[s] = __builtin_bit_cast(bf16x8, u);
        }
    }

    // ---- q = Wq @ x^T (swapped): D col = token, row = out-feature ----
    f32x16 qD[8];
    #pragma unroll
    for (int nt = 0; nt < 8; ++nt) qD[nt] = (f32x16)(0.f);
    #pragma unroll
    for (int nt = 0; nt < 8; ++nt) {
        #pragma unroll
        for (int s = 0; s < 16; ++s) {
            const bf16x8 wa = *reinterpret_cast<const bf16x8*>(
                wq_bf + (size_t)(32 * nt + lo) * HWF + 16 * s + 8 * hi);
            qD[nt] = MFMA32(wa, xB[s], qD[nt]);
        }
    }

    // ---- per-token stats fully in-lane (own half + partner half) ----
    float qs = 0.f, qss = 0.f;
    #pragma unroll
    for (int nt = 0; nt < 8; ++nt)
        #pragma unroll
        for (int i = 0; i < 16; ++i) {
            const float v = qD[nt][i];
            qs += v; qss = __builtin_fmaf(v, v, qss);
        }
    qs += __shfl_xor(qs, 32);
    qss += __shfl_xor(qss, 32);
    const float qm  = qs * (1.f / HWF);
    const float qv  = (qss - qs * qs * (1.f / HWF)) * (1.f / (HWF - 1));
    const float qm2 = qm * qm;

    // ---- qA frags in-register: cvt_pk pairs + permlane32_swap ----
    bf16x8 qA[16];
    #pragma unroll
    for (int nt = 0; nt < 8; ++nt) {
        unsigned w[8];
        #pragma unroll
        for (int p = 0; p < 8; ++p) w[p] = cvtpk(qD[nt][2 * p], qD[nt][2 * p + 1]);
        #pragma unroll
        for (int h = 0; h < 2; ++h) {
            unsigned a0 = w[4 * h + 0], b0 = w[4 * h + 2];
            unsigned a1 = w[4 * h + 1], b1 = w[4 * h + 3];
            plswap(a0, b0); plswap(a1, b1);
            uint4v u; u[0] = a0; u[1] = a1; u[2] = b0; u[3] = b1;
            qA[2 * nt + h] = __builtin_bit_cast(bf16x8, u);
        }
    }

    // ---- main loop over 32 j-tiles ----
    f32x16 O4[8];
    #pragma unroll
    for (int ct = 0; ct < 8; ++ct) O4[ct] = (f32x16)(0.f);
    float l = 0.f;
    const int rx = (lo & 7);                // K xor-swizzle key
    const int vx = (lo >> 1) & 3;           // V xor-swizzle key (banks 32-covered)

    for (int jt = 0; jt < NT; ++jt) {
        const int cur = jt & 1;
        const int kb = cur ? KB1 : KB0, vb = cur ? VB1 : VB0;
        const int kbn = cur ? KB0 : KB1, vbn = cur ? VB0 : VB1;
        __syncthreads();                    // drains DMA(jt); prev tile reads done
        if (jt + 1 < NT) {                  // prefetch stays in flight across compute
            dma_tile16(kblob + (size_t)(jt + 1) * 8192, smem, kbn, wave, lane);
            dma_tile16(vblob + (size_t)(jt + 1) * 8192, smem, vbn, wave, lane);
        }

        // ---- S = K @ q^T : two independent MFMA chains ----
        f32x16 sacc0 = (f32x16)(0.f), sacc1 = (f32x16)(0.f);
        __builtin_amdgcn_s_setprio(1);
        #pragma unroll
        for (int s = 0; s < 16; s += 2) {
            const bf16x8 k0 = *reinterpret_cast<const bf16x8*>(
                smem + kb + lo * 512 + (((2 * s + hi) ^ rx) * 16));
            const bf16x8 k1 = *reinterpret_cast<const bf16x8*>(
                smem + kb + lo * 512 + (((2 * s + 2 + hi) ^ rx) * 16));
            sacc0 = MFMA32(k0, qA[s], sacc0);
            sacc1 = MFMA32(k1, qA[s + 1], sacc1);
        }
        __builtin_amdgcn_s_setprio(0);

        // ---- ssim -> p -> packed bf16 pairs (stats via row-vector reads) ----
        unsigned pw[8];
        #pragma unroll
        for (int g = 0; g < 4; ++g) {
            const int soff = (32 * jt + 8 * g + 4 * hi) * 4;
            const f32x4 a4 = *reinterpret_cast<const f32x4*>(smem + STATS + soff);
            const f32x4 b4 = *reinterpret_cast<const f32x4*>(smem + STATS + 4096 + soff);
            const f32x4 c4 = *reinterpret_cast<const f32x4*>(smem + STATS + 8192 + soff);
            float pr[4];
            #pragma unroll
            for (int q = 0; q < 4; ++q) {
                const int i = 4 * g + q;
                const float sv = sacc0[i] + sacc1[i];
                const float cov2 = __builtin_fmaf(sv, 2.f * RK, C2v);
                const float num  = __builtin_fmaf(a4[q], qm, C1v) * cov2;
                const float den  = __builtin_fmaf(qm2 + b4[q], qv + c4[q], EPSv);
                pr[q] = __expf(__fdividef(num, den));
                l += pr[q];
            }
            pw[2 * g]     = cvtpk(pr[0], pr[1]);
            pw[2 * g + 1] = cvtpk(pr[2], pr[3]);
        }

        // ---- O += P @ V : A-frags via permlane32_swap, B from LDS ----
        #pragma unroll
        for (int h = 0; h < 2; ++h) {
            unsigned a0 = pw[4 * h + 0], b0 = pw[4 * h + 2];
            unsigned a1 = pw[4 * h + 1], b1 = pw[4 * h + 3];
            plswap(a0, b0); plswap(a1, b1);
            uint4v u; u[0] = a0; u[1] = a1; u[2] = b0; u[3] = b1;
            const bf16x8 pa = __builtin_bit_cast(bf16x8, u);
            __builtin_amdgcn_s_setprio(1);
            #pragma unroll
            for (int ct = 0; ct < 8; ++ct) {
                const bf16x8 vfr = *reinterpret_cast<const bf16x8*>(
                    smem + vb + (32 * ct + lo) * 64 + (((2 * h + hi) ^ vx) * 16));
                O4[ct] = MFMA32(pa, vfr, O4[ct]);
            }
            __builtin_amdgcn_s_setprio(0);
        }
    }

    // ---- l: lane-sum -> per-row via tiny wave-local LDS redistribute ----
    const float lf = l + __shfl_xor(l, 32);
    if (hi == 0)
        *reinterpret_cast<float*>(smem + LRED + (wave * 32 + lo) * 4) = lf;
    // same-wave DS ops complete in order; reads below see the writes
    float rl[16];
    #pragma unroll
    for (int g = 0; g < 4; ++g) {
        const f32x4 lv = *reinterpret_cast<const f32x4*>(
            smem + LRED + wave * 128 + (8 * g + 4 * hi) * 4);
        rl[4 * g + 0] = 1.f / lv[0];
        rl[4 * g + 1] = 1.f / lv[1];
        rl[4 * g + 2] = 1.f / lv[2];
        rl[4 * g + 3] = 1.f / lv[3];
    }

    #pragma unroll
    for (int ct = 0; ct < 8; ++ct) {
        #pragma unroll
        for (int i = 0; i < 16; ++i) {
            const int row = 32 * rg + (i & 3) + 8 * (i >> 2) + 4 * hi;
            out[(size_t)(n0 + row) * HWF + 32 * ct + lo] = O4[ct][i] * rl[i];
        }
    }
}

extern "C" void kernel_launch(void* const* d_in, const int* in_sizes, int n_in,
                              void* d_out, int out_size, void* d_ws, size_t ws_size,
                              hipStream_t stream) {
    (void)in_sizes; (void)n_in; (void)out_size; (void)ws_size;
    const float* x   = (const float*)d_in[0];
    const float* mem = (const float*)d_in[1];
    const float* Wq  = (const float*)d_in[2];
    const float* Wk  = (const float*)d_in[3];
    const float* Wv  = (const float*)d_in[4];
    float* out = (float*)d_out;

    // workspace (~1.2 MB): wq_bf | kblob | vblob | sblob (SoA: sa|sb|sc)
    short* wq_bf = (short*)d_ws;                        // 65536
    short* kblob = wq_bf + 65536;                       // 262144 (32 tiles x 8192)
    short* vblob = kblob + (size_t)MEMD * HWF;          // 262144
    float* sblob = (float*)(vblob + (size_t)MEMD * HWF);  // 3072 floats

    // W^T scratch lives in the head of `out` (64 MB): written by prep_w,
    // read by prep_kv, fully overwritten later by attn. Same-stream ordering
    // makes this safe under graph capture.
    float* WkT = out;                                   // 65536 floats (256 KB)
    float* WvT = out + 65536;                           // 65536 floats (256 KB)

    prep_w<<<40, 256, 0, stream>>>(Wq, Wk, Wv, wq_bf, WkT, WvT);
    prep_kv<<<MEMD / 8, 256, 0, stream>>>(mem, WkT, WvT, kblob, vblob, sblob);
    attn<<<NROWS / TM, THREADS, 0, stream>>>(x, wq_bf, kblob, vblob, sblob, out);
}

// Round 4
// 264.793 us; speedup vs baseline: 1.2408x; 1.2408x over previous
//
#include <hip/hip_runtime.h>
#include <math.h>

typedef __attribute__((ext_vector_type(8)))  short bf16x8;   // 8 bf16 = 4 VGPR
typedef __attribute__((ext_vector_type(16))) float f32x16;   // 32x32 MFMA acc
typedef __attribute__((ext_vector_type(4)))  float f32x4;
typedef __attribute__((ext_vector_type(4)))  unsigned uint4v;

#define MFMA32(a, b, c) __builtin_amdgcn_mfma_f32_32x32x16_bf16((a), (b), (c), 0, 0, 0)

namespace {
constexpr int HWF   = 256;
constexpr int MEMD  = 1024;
constexpr int NROWS = 65536;
constexpr int TM    = 128;          // token rows per block: 4 waves x 32 rows
constexpr int NT    = MEMD / 32;    // 32 j-tiles of 32
constexpr int THREADS = 256;        // 4 waves -> 2 blocks/CU
constexpr float C1v  = 0.01f;
constexpr float C2v  = 0.03f;
constexpr float EPSv = 1e-8f;
constexpr float RK   = 1.0f / 255.0f;

// LDS map (bytes): K dbuf | V dbuf | stats (one-shot SoA) | l-redistribute
constexpr int KB0 = 0;              // 16 KB K tile (32 rows x 512B, xor-swizzled)
constexpr int KB1 = 16384;
constexpr int VB0 = 32768;          // 16 KB V tile (256 rows x 64B, xor-swizzled)
constexpr int VB1 = 49152;
constexpr int STATS = 65536;        // 12 KB: sa[1024] | sb[1024] | sc[1024]
constexpr int LRED  = STATS + 12288;  // 4 waves x 32 x f32 = 512 B
constexpr int SMEM_SZ = LRED + 512;   // 78336 B -> 2 blocks/CU
}

__device__ __forceinline__ short f2bf(float f) {            // RNE float->bf16
    union { float f; unsigned u; } v; v.f = f;
    unsigned r = v.u + 0x7fffu + ((v.u >> 16) & 1u);
    return (short)(r >> 16);
}

// packed f32 pair -> 2 bf16 in one u32 (src0 -> [15:0], src1 -> [31:16]), RNE
__device__ __forceinline__ unsigned cvtpk(float a, float b) {
    unsigned r;
    asm("v_cvt_pk_bf16_f32 %0, %1, %2" : "=v"(r) : "v"(a), "v"(b));
    return r;
}

// v_permlane32_swap_b32: a.lanes[32..63] <-> b.lanes[0..31].
__device__ __forceinline__ void plswap(unsigned &a, unsigned &b) {
#if defined(__has_builtin) && __has_builtin(__builtin_amdgcn_permlane32_swap)
    auto r = __builtin_amdgcn_permlane32_swap((int)a, (int)b, false, false);
    a = (unsigned)r[0]; b = (unsigned)r[1];
#else
    const bool h = (threadIdx.x & 32) != 0;
    const unsigned ax = (unsigned)__shfl_xor((int)a, 32);
    const unsigned bx = (unsigned)__shfl_xor((int)b, 32);
    const unsigned na = h ? bx : a;
    const unsigned nb = h ? b : ax;
    a = na; b = nb;
#endif
}

// async global->LDS DMA: 16 KB tile, wave w (of 4) copies [w*4096, w*4096+4096)
__device__ __forceinline__ void dma_tile16(const short* gbase, char* smem, int ldsbase,
                                           int wave, int lane) {
    const char* g = (const char*)gbase + wave * 4096 + lane * 16;
    char* l = smem + ldsbase + wave * 4096;
    #pragma unroll
    for (int i = 0; i < 4; ++i) {
        __builtin_amdgcn_global_load_lds(
            (const __attribute__((address_space(1))) unsigned int*)(g + i * 1024),
            (__attribute__((address_space(3))) unsigned int*)(l + i * 1024), 16, 0, 0);
    }
}

// ---------------------------------------------------------------------------
// cast_w: Wq/Wk/Wv -> bf16 (blocks 0-31: Wq, 32-63: Wk, 64-95: Wv)
// ---------------------------------------------------------------------------
__global__ __launch_bounds__(256) void cast_w(
    const float* __restrict__ Wq, const float* __restrict__ Wk,
    const float* __restrict__ Wv, short* __restrict__ wq_bf,
    short* __restrict__ wk_bf, short* __restrict__ wv_bf)
{
    const int b = blockIdx.x, t = threadIdx.x;
    const float* src = (b < 32) ? Wq : (b < 64) ? Wk : Wv;
    short* dst = (b < 32) ? wq_bf : (b < 64) ? wk_bf : wv_bf;
    const int i = (b & 31) * 2048 + t * 8;
    const float4 a = *reinterpret_cast<const float4*>(src + i);
    const float4 c = *reinterpret_cast<const float4*>(src + i + 4);
    uint4v u;
    u[0] = cvtpk(a.x, a.y); u[1] = cvtpk(a.z, a.w);
    u[2] = cvtpk(c.x, c.y); u[3] = cvtpk(c.z, c.w);
    *reinterpret_cast<uint4v*>(dst + i) = u;
}

// ---------------------------------------------------------------------------
// prep_mfma: k = m@Wk^T and v = m@Wv^T via MFMA (same swapped-operand frag
// pattern as attn's q-projection: A = W rows, B = mem rows -> D col = j).
// Blocks 0-7: K half (stats + centered-K blob). Blocks 8-15: V blob.
// Blob byte layouts identical to the previous fp32 prep (attn unchanged).
// MFMA 32x32x16: A[m=lane&31][k=8*hi+e], B[k=8*hi+e][n=lane&31],
//                D col=lane&31, row=(i&3)+8*(i>>2)+4*hi (+32*nt).
// ---------------------------------------------------------------------------
__global__ __launch_bounds__(256) void prep_mfma(
    const float* __restrict__ mem, const short* __restrict__ wk_bf,
    const short* __restrict__ wv_bf, short* __restrict__ kblob,
    short* __restrict__ vblob, float* __restrict__ sblob)
{
    const int t = threadIdx.x, wave = t >> 6, lane = t & 63;
    const int lo = lane & 31, hi = lane >> 5;
    const bool isV = blockIdx.x >= 8;
    const int jb = (blockIdx.x & 7) * 128 + wave * 32;  // wave's 32 j-rows
    const int j  = jb + lo;                              // this lane's j (D col)

    // B-frags from mem rows (fp32 -> bf16 in-register)
    bf16x8 mB[16];
    {
        const float* mr = mem + (size_t)j * HWF;
        #pragma unroll
        for (int s = 0; s < 16; ++s) {
            const float4 a = *reinterpret_cast<const float4*>(mr + 16 * s + 8 * hi);
            const float4 b = *reinterpret_cast<const float4*>(mr + 16 * s + 8 * hi + 4);
            uint4v u;
            u[0] = cvtpk(a.x, a.y); u[1] = cvtpk(a.z, a.w);
            u[2] = cvtpk(b.x, b.y); u[3] = cvtpk(b.z, b.w);
            mB[s] = __builtin_bit_cast(bf16x8, u);
        }
    }

    const short* W = isV ? wv_bf : wk_bf;
    f32x16 D[8];
    #pragma unroll
    for (int nt = 0; nt < 8; ++nt) D[nt] = (f32x16)(0.f);
    #pragma unroll
    for (int nt = 0; nt < 8; ++nt) {
        #pragma unroll
        for (int s = 0; s < 16; ++s) {
            const bf16x8 wa = *reinterpret_cast<const bf16x8*>(
                W + (size_t)(32 * nt + lo) * HWF + 16 * s + 8 * hi);
            D[nt] = MFMA32(wa, mB[s], D[nt]);
        }
    }

    const int jt = jb >> 5, ro = lo;        // jb is a multiple of 32
    if (!isV) {
        // per-j stats (in-lane over 128 regs + partner half)
        float s = 0.f, ss = 0.f;
        #pragma unroll
        for (int nt = 0; nt < 8; ++nt)
            #pragma unroll
            for (int i = 0; i < 16; ++i) {
                const float v = D[nt][i];
                s += v; ss = __builtin_fmaf(v, v, ss);
            }
        s += __shfl_xor(s, 32);
        ss += __shfl_xor(ss, 32);
        const float km = s * (1.f / HWF);
        const float kv = (ss - s * s * (1.f / HWF)) * (1.f / (HWF - 1));
        // K blob: [jt][ro][512B: chunk(f>>3)^(ro&7)][8 bf16]; f = 32nt+8a+4hi+e
        #pragma unroll
        for (int nt = 0; nt < 8; ++nt) {
            #pragma unroll
            for (int a = 0; a < 4; ++a) {
                short4 q4;
                q4.x = f2bf(D[nt][4 * a + 0] - km);
                q4.y = f2bf(D[nt][4 * a + 1] - km);
                q4.z = f2bf(D[nt][4 * a + 2] - km);
                q4.w = f2bf(D[nt][4 * a + 3] - km);
                *reinterpret_cast<short4*>(
                    kblob + jt * 8192 + ro * 256 +
                    (((4 * nt + a) ^ (ro & 7)) * 8) + 4 * hi) = q4;
            }
        }
        if (hi == 0) {
            sblob[j]        = 2.f * km;
            sblob[1024 + j] = km * km + C1v;
            sblob[2048 + j] = kv + C2v;
        }
    } else {
        // V blob: [jt][f][64B: chunk(j>>3)^((f>>1)&3)][8 bf16 over j]
        #pragma unroll
        for (int nt = 0; nt < 8; ++nt) {
            #pragma unroll
            for (int i = 0; i < 16; ++i) {
                const int f = 32 * nt + (i & 3) + 8 * (i >> 2) + 4 * hi;
                vblob[jt * 8192 + f * 32 +
                      (((ro >> 3) ^ ((f >> 1) & 3)) * 8) + (ro & 7)] = f2bf(D[nt][i]);
            }
        }
    }
}

// ---------------------------------------------------------------------------
// attn: TM=128 rows/block, 4 waves, 2 blocks/CU. Swapped-operand MFMA chain
// keeps P in registers. Round-4: single QK accumulator chain (round-3 split
// regressed: +32 live VGPRs through softmax), V swizzle keyed (c>>1)&3 kept.
// MFMA 32x32x16 layouts (HW-verified m74/m101):
//   A[m=lane&31][k=8*(lane>>5)+e], B[k=8*(lane>>5)+e][n=lane&31],
//   D col=lane&31, row=(reg&3)+8*(reg>>2)+4*(lane>>5).
// ---------------------------------------------------------------------------
__global__ __launch_bounds__(THREADS, 2) void attn(
    const float* __restrict__ x, const short* __restrict__ wq_bf,
    const short* __restrict__ kblob, const short* __restrict__ vblob,
    const float* __restrict__ sblob, float* __restrict__ out)
{
    __shared__ __align__(16) char smem[SMEM_SZ];
    const int t = threadIdx.x, wave = t >> 6, lane = t & 63;
    const int lo = lane & 31, hi = lane >> 5;
    const int rg = wave;                    // 4 row-groups of 32 tokens
    const int n0 = blockIdx.x * TM;
    const int tok = n0 + 32 * rg + lo;      // this lane's token row

    // ---- DMA tile 0 + one-shot stats immediately (overlaps whole prologue) ----
    dma_tile16(kblob, smem, KB0, wave, lane);
    dma_tile16(vblob, smem, VB0, wave, lane);
    #pragma unroll
    for (int r = 0; r < 3; ++r) {           // 12 KB stats: 3 rounds x 4 waves x 1 KB
        __builtin_amdgcn_global_load_lds(
            (const __attribute__((address_space(1))) unsigned int*)
                ((const char*)sblob + r * 4096 + wave * 1024 + lane * 16),
            (__attribute__((address_space(3))) unsigned int*)
                (smem + STATS + r * 4096 + wave * 1024 + lane * 16), 16, 0, 0);
    }

    // ---- x B-frags: lane = token (n index), regs = feature ----
    bf16x8 xB[16];
    {
        const float* xr = x + (size_t)tok * HWF;
        #pragma unroll
        for (int s = 0; s < 16; ++s) {
            const float4 a = *reinterpret_cast<const float4*>(xr + 16 * s + 8 * hi);
            const float4 b = *reinterpret_cast<const float4*>(xr + 16 * s + 8 * hi + 4);
            uint4v u;
            u[0] = cvtpk(a.x, a.y); u[1] = cvtpk(a.z, a.w);
            u[2] = cvtpk(b.x, b.y); u[3] = cvtpk(b.z, b.w);
            xB[s] = __builtin_bit_cast(bf16x8, u);
        }
    }

    // ---- q = Wq @ x^T (swapped): D col = token, row = out-feature ----
    f32x16 qD[8];
    #pragma unroll
    for (int nt = 0; nt < 8; ++nt) qD[nt] = (f32x16)(0.f);
    #pragma unroll
    for (int nt = 0; nt < 8; ++nt) {
        #pragma unroll
        for (int s = 0; s < 16; ++s) {
            const bf16x8 wa = *reinterpret_cast<const bf16x8*>(
                wq_bf + (size_t)(32 * nt + lo) * HWF + 16 * s + 8 * hi);
            qD[nt] = MFMA32(wa, xB[s], qD[nt]);
        }
    }

    // ---- per-token stats fully in-lane (own half + partner half) ----
    float qs = 0.f, qss = 0.f;
    #pragma unroll
    for (int nt = 0; nt < 8; ++nt)
        #pragma unroll
        for (int i = 0; i < 16; ++i) {
            const float v = qD[nt][i];
            qs += v; qss = __builtin_fmaf(v, v, qss);
        }
    qs += __shfl_xor(qs, 32);
    qss += __shfl_xor(qss, 32);
    const float qm  = qs * (1.f / HWF);
    const float qv  = (qss - qs * qs * (1.f / HWF)) * (1.f / (HWF - 1));
    const float qm2 = qm * qm;

    // ---- qA frags in-register: cvt_pk pairs + permlane32_swap ----
    bf16x8 qA[16];
    #pragma unroll
    for (int nt = 0; nt < 8; ++nt) {
        unsigned w[8];
        #pragma unroll
        for (int p = 0; p < 8; ++p) w[p] = cvtpk(qD[nt][2 * p], qD[nt][2 * p + 1]);
        #pragma unroll
        for (int h = 0; h < 2; ++h) {
            unsigned a0 = w[4 * h + 0], b0 = w[4 * h + 2];
            unsigned a1 = w[4 * h + 1], b1 = w[4 * h + 3];
            plswap(a0, b0); plswap(a1, b1);
            uint4v u; u[0] = a0; u[1] = a1; u[2] = b0; u[3] = b1;
            qA[2 * nt + h] = __builtin_bit_cast(bf16x8, u);
        }
    }

    // ---- main loop over 32 j-tiles ----
    f32x16 O4[8];
    #pragma unroll
    for (int ct = 0; ct < 8; ++ct) O4[ct] = (f32x16)(0.f);
    float l = 0.f;
    const int rx = (lo & 7);                // K xor-swizzle key
    const int vx = (lo >> 1) & 3;           // V xor-swizzle key (full bank coverage)

    for (int jt = 0; jt < NT; ++jt) {
        const int cur = jt & 1;
        const int kb = cur ? KB1 : KB0, vb = cur ? VB1 : VB0;
        const int kbn = cur ? KB0 : KB1, vbn = cur ? VB0 : VB1;
        __syncthreads();                    // drains DMA(jt); prev tile reads done
        if (jt + 1 < NT) {                  // prefetch stays in flight across compute
            dma_tile16(kblob + (size_t)(jt + 1) * 8192, smem, kbn, wave, lane);
            dma_tile16(vblob + (size_t)(jt + 1) * 8192, smem, vbn, wave, lane);
        }

        // ---- S = K @ q^T : lane = token, regs = j-offset (32 j) ----
        f32x16 sacc = (f32x16)(0.f);
        __builtin_amdgcn_s_setprio(1);
        #pragma unroll
        for (int s = 0; s < 16; ++s) {
            const bf16x8 kfr = *reinterpret_cast<const bf16x8*>(
                smem + kb + lo * 512 + (((2 * s + hi) ^ rx) * 16));
            sacc = MFMA32(kfr, qA[s], sacc);
        }
        __builtin_amdgcn_s_setprio(0);

        // ---- ssim -> p -> packed bf16 pairs (stats via row-vector reads) ----
        unsigned pw[8];
        #pragma unroll
        for (int g = 0; g < 4; ++g) {
            const int soff = (32 * jt + 8 * g + 4 * hi) * 4;
            const f32x4 a4 = *reinterpret_cast<const f32x4*>(smem + STATS + soff);
            const f32x4 b4 = *reinterpret_cast<const f32x4*>(smem + STATS + 4096 + soff);
            const f32x4 c4 = *reinterpret_cast<const f32x4*>(smem + STATS + 8192 + soff);
            float pr[4];
            #pragma unroll
            for (int q = 0; q < 4; ++q) {
                const int i = 4 * g + q;
                const float cov2 = __builtin_fmaf(sacc[i], 2.f * RK, C2v);
                const float num  = __builtin_fmaf(a4[q], qm, C1v) * cov2;
                const float den  = __builtin_fmaf(qm2 + b4[q], qv + c4[q], EPSv);
                pr[q] = __expf(__fdividef(num, den));
                l += pr[q];
            }
            pw[2 * g]     = cvtpk(pr[0], pr[1]);
            pw[2 * g + 1] = cvtpk(pr[2], pr[3]);
        }

        // ---- O += P @ V : A-frags via permlane32_swap, B from LDS ----
        #pragma unroll
        for (int h = 0; h < 2; ++h) {
            unsigned a0 = pw[4 * h + 0], b0 = pw[4 * h + 2];
            unsigned a1 = pw[4 * h + 1], b1 = pw[4 * h + 3];
            plswap(a0, b0); plswap(a1, b1);
            uint4v u; u[0] = a0; u[1] = a1; u[2] = b0; u[3] = b1;
            const bf16x8 pa = __builtin_bit_cast(bf16x8, u);
            __builtin_amdgcn_s_setprio(1);
            #pragma unroll
            for (int ct = 0; ct < 8; ++ct) {
                const bf16x8 vfr = *reinterpret_cast<const bf16x8*>(
                    smem + vb + (32 * ct + lo) * 64 + (((2 * h + hi) ^ vx) * 16));
                O4[ct] = MFMA32(pa, vfr, O4[ct]);
            }
            __builtin_amdgcn_s_setprio(0);
        }
    }

    // ---- l: lane-sum -> per-row via tiny wave-local LDS redistribute ----
    const float lf = l + __shfl_xor(l, 32);
    if (hi == 0)
        *reinterpret_cast<float*>(smem + LRED + (wave * 32 + lo) * 4) = lf;
    // same-wave DS ops complete in order; reads below see the writes
    float rl[16];
    #pragma unroll
    for (int g = 0; g < 4; ++g) {
        const f32x4 lv = *reinterpret_cast<const f32x4*>(
            smem + LRED + wave * 128 + (8 * g + 4 * hi) * 4);
        rl[4 * g + 0] = 1.f / lv[0];
        rl[4 * g + 1] = 1.f / lv[1];
        rl[4 * g + 2] = 1.f / lv[2];
        rl[4 * g + 3] = 1.f / lv[3];
    }

    #pragma unroll
    for (int ct = 0; ct < 8; ++ct) {
        #pragma unroll
        for (int i = 0; i < 16; ++i) {
            const int row = 32 * rg + (i & 3) + 8 * (i >> 2) + 4 * hi;
            out[(size_t)(n0 + row) * HWF + 32 * ct + lo] = O4[ct][i] * rl[i];
        }
    }
}

extern "C" void kernel_launch(void* const* d_in, const int* in_sizes, int n_in,
                              void* d_out, int out_size, void* d_ws, size_t ws_size,
                              hipStream_t stream) {
    (void)in_sizes; (void)n_in; (void)out_size; (void)ws_size;
    const float* x   = (const float*)d_in[0];
    const float* mem = (const float*)d_in[1];
    const float* Wq  = (const float*)d_in[2];
    const float* Wk  = (const float*)d_in[3];
    const float* Wv  = (const float*)d_in[4];
    float* out = (float*)d_out;

    // workspace (~1.2 MB): wq_bf | kblob | vblob | sblob (SoA: sa|sb|sc)
    short* wq_bf = (short*)d_ws;                        // 65536
    short* kblob = wq_bf + 65536;                       // 262144 (32 tiles x 8192)
    short* vblob = kblob + (size_t)MEMD * HWF;          // 262144
    float* sblob = (float*)(vblob + (size_t)MEMD * HWF);  // 3072 floats

    // Wk/Wv bf16 scratch lives in the head of `out` (64 MB): written by
    // cast_w, read by prep_mfma, fully overwritten later by attn.
    // Same-stream ordering makes this safe under graph capture.
    short* wk_bf = (short*)out;                         // 65536 shorts (128 KB)
    short* wv_bf = wk_bf + 65536;                       // 65536 shorts (128 KB)

    cast_w<<<96, 256, 0, stream>>>(Wq, Wk, Wv, wq_bf, wk_bf, wv_bf);
    prep_mfma<<<16, 256, 0, stream>>>(mem, wk_bf, wv_bf, kblob, vblob, sblob);
    attn<<<NROWS / TM, THREADS, 0, stream>>>(x, wq_bf, kblob, vblob, sblob, out);
}